// Round 4
// baseline (481.086 us; speedup 1.0000x reference)
//
#include <hip/hip_runtime.h>
#include <hip/hip_bf16.h>

#define DI __device__ __forceinline__

typedef __attribute__((ext_vector_type(8))) short bf16x8;
typedef __attribute__((ext_vector_type(4))) short bf16x4;
typedef __attribute__((ext_vector_type(4))) float f32x4;

static constexpr int B_ = 2, Q_ = 1024, MM_ = 1024, K_ = 2048, D_ = 1024, H_ = 16, DK_ = 64, D3_ = 3072;

DI unsigned short f2bf(float f) {
  unsigned int x = __builtin_bit_cast(unsigned int, f);
  x += 0x7fffu + ((x >> 16) & 1u);
  return (unsigned short)(x >> 16);
}
DI float bf2f(unsigned short u) {
  unsigned int x = ((unsigned int)u) << 16;
  return __builtin_bit_cast(float, x);
}
DI void gload_lds16(const void* g, void* l) {
  __builtin_amdgcn_global_load_lds((const __attribute__((address_space(1))) unsigned int*)g,
                                   (__attribute__((address_space(3))) unsigned int*)l, 16, 0, 0);
}
DI bf16x8 ld8(const unsigned short* p) { return *(const bf16x8*)p; }

// ---------------- prep: convert inputs to bf16 ----------------
__global__ __launch_bounds__(256) void k_convert(const float* __restrict__ xin,
                                                 const float* __restrict__ xmem,
                                                 const float* __restrict__ rin,
                                                 unsigned short* __restrict__ xcat,
                                                 unsigned short* __restrict__ rbf) {
  const int64_t nx = (int64_t)B_ * K_ * D_ / 4;
  const int64_t nr = (int64_t)K_ * D_ / 4;
  int64_t idx = (int64_t)blockIdx.x * 256 + threadIdx.x;
  const float* src;
  unsigned short* dst;
  if (idx < nx) {
    int64_t e = idx * 4;
    int d = (int)(e & (D_ - 1));
    int64_t t = e >> 10;
    int kpos = (int)(t & (K_ - 1));
    int b = (int)(t >> 11);
    src = (kpos < MM_) ? xmem + ((int64_t)b * MM_ + kpos) * D_ + d
                       : xin + ((int64_t)b * Q_ + (kpos - MM_)) * D_ + d;
    dst = xcat + e;
  } else if (idx < nx + nr) {
    int64_t e = (idx - nx) * 4;
    src = rin + e;
    dst = rbf + e;
  } else {
    return;
  }
  float4 fv = *(const float4*)src;
  dst[0] = f2bf(fv.x); dst[1] = f2bf(fv.y); dst[2] = f2bf(fv.z); dst[3] = f2bf(fv.w);
}

// ---------------- prep: transpose+convert a weight (R x C f32 -> C x R bf16) ----
__global__ __launch_bounds__(256) void k_transw(const float* __restrict__ src,
                                                unsigned short* __restrict__ dst, int R, int C) {
  __shared__ float t[32][33];
  const int c0 = blockIdx.x * 32, r0 = blockIdx.y * 32;
  const int tx = threadIdx.x & 31, ty = threadIdx.x >> 5;
#pragma unroll
  for (int i = 0; i < 32; i += 8) t[ty + i][tx] = src[(int64_t)(r0 + ty + i) * C + c0 + tx];
  __syncthreads();
#pragma unroll
  for (int i = 0; i < 32; i += 8)
    dst[(int64_t)(c0 + ty + i) * R + r0 + tx] = f2bf(t[tx][ty + i]);
}

// ---------------- 128x128 bf16 GEMM: C = A(Mx1024) * Bw(Nx1024)^T ----------------
// EPI 0: QKV scatter (o0=qh,o1=kh,o2=vt)   EPI 1: rh scatter (o0=rh)   EPI 2: f32 out (of)
template <int EPI>
__global__ __launch_bounds__(256) void k_gemm128(const unsigned short* __restrict__ A,
                                                 const unsigned short* __restrict__ Bw,
                                                 unsigned short* __restrict__ o0,
                                                 unsigned short* __restrict__ o1,
                                                 unsigned short* __restrict__ o2,
                                                 float* __restrict__ of) {
  __shared__ unsigned short sA[2][128 * 32];
  __shared__ unsigned short sB[2][128 * 32];
  const int tid = threadIdx.x, w = tid >> 6, l = tid & 63;
  const int l15 = l & 15, lg = l >> 4;
  const int bm = blockIdx.x, bn = blockIdx.y;
  const int qr = (w >> 1) * 64, qc = (w & 1) * 64;
  const int srow = w * 16 + (l >> 2);
  const int skel = (l & 3) * 8;

  const unsigned short* Ab = A + (int64_t)(bm * 128) * D_;
  const unsigned short* Bb = Bw + (int64_t)(bn * 128) * D_;

  const f32x4 zero = {0.f, 0.f, 0.f, 0.f};
  f32x4 acc[4][4];
#pragma unroll
  for (int i = 0; i < 4; ++i)
#pragma unroll
    for (int j = 0; j < 4; ++j) acc[i][j] = zero;

  auto stage = [&](int buf, int kt) {
    int kb = kt * 32 + skel;
#pragma unroll
    for (int rr = 0; rr < 2; ++rr) {
      int row = rr * 64 + srow;
      gload_lds16(Ab + (int64_t)row * D_ + kb, &sA[buf][row * 32 + skel]);
      gload_lds16(Bb + (int64_t)row * D_ + kb, &sB[buf][row * 32 + skel]);
    }
  };

  stage(0, 0);
  __syncthreads();
  int buf = 0;
  const int nkt = D_ / 32;
  for (int kt = 0; kt < nkt; ++kt) {
    if (kt + 1 < nkt) stage(buf ^ 1, kt + 1);
    bf16x8 af[4], bfr[4];
#pragma unroll
    for (int i = 0; i < 4; ++i) {
      af[i] = *(const bf16x8*)&sA[buf][(qr + i * 16 + l15) * 32 + lg * 8];
      bfr[i] = *(const bf16x8*)&sB[buf][(qc + i * 16 + l15) * 32 + lg * 8];
    }
#pragma unroll
    for (int i = 0; i < 4; ++i)
#pragma unroll
      for (int j = 0; j < 4; ++j)
        acc[i][j] = __builtin_amdgcn_mfma_f32_16x16x32_bf16(af[i], bfr[j], acc[i][j], 0, 0, 0);
    __syncthreads();
    buf ^= 1;
  }

#pragma unroll
  for (int i = 0; i < 4; ++i) {
#pragma unroll
    for (int j = 0; j < 4; ++j) {
      const int gr0 = bm * 128 + qr + i * 16 + lg * 4;
      const int gc = bn * 128 + qc + j * 16 + l15;
      if constexpr (EPI == 2) {
#pragma unroll
        for (int r = 0; r < 4; ++r) of[(int64_t)(gr0 + r) * D_ + gc] = acc[i][j][r];
      } else if constexpr (EPI == 1) {
        const int hh = gc >> 6, d = gc & 63;
#pragma unroll
        for (int r = 0; r < 4; ++r)
          o0[((int64_t)hh * K_ + gr0 + r) * DK_ + d] = f2bf(acc[i][j][r]);
      } else {
        const int sel = gc >> 6, d = gc & 63;
        const int ty = sel >> 4, hh = sel & 15;
        const int bb = gr0 >> 11, kp0 = gr0 & (K_ - 1);
        if (ty == 0) {
#pragma unroll
          for (int r = 0; r < 4; ++r) {
            int kp = kp0 + r;
            if (kp >= MM_)
              o0[(((int64_t)bb * H_ + hh) * Q_ + (kp - MM_)) * DK_ + d] = f2bf(acc[i][j][r]);
          }
        } else if (ty == 1) {
#pragma unroll
          for (int r = 0; r < 4; ++r)
            o1[(((int64_t)bb * H_ + hh) * K_ + kp0 + r) * DK_ + d] = f2bf(acc[i][j][r]);
        } else {
          bf16x4 tv;
#pragma unroll
          for (int r = 0; r < 4; ++r) tv[r] = (short)f2bf(acc[i][j][r]);
          *(bf16x4*)(o2 + (((int64_t)bb * H_ + hh) * DK_ + d) * K_ + kp0) = tv;
        }
      }
    }
  }
}

// ---------------- rank-1 biases: u.k_j and v.r_p ----------------
__global__ __launch_bounds__(256) void k_bias(const unsigned short* __restrict__ kh,
                                              const unsigned short* __restrict__ rh,
                                              const float* __restrict__ u,
                                              const float* __restrict__ v,
                                              float* __restrict__ biask,
                                              float* __restrict__ biasr) {
  int gid = blockIdx.x * 256 + threadIdx.x;
  const int nk = B_ * H_ * K_;
  const unsigned short* row;
  const float* uv;
  float* outp;
  if (gid < nk) {
    int h = (gid >> 11) & (H_ - 1);
    row = kh + (int64_t)gid * DK_;
    uv = u + h * DK_;
    outp = biask + gid;
  } else if (gid < nk + H_ * K_) {
    int g = gid - nk;
    int h = g >> 11;
    row = rh + (int64_t)g * DK_;
    uv = v + h * DK_;
    outp = biasr + g;
  } else {
    return;
  }
  float s = 0.f;
#pragma unroll
  for (int d0 = 0; d0 < DK_; d0 += 8) {
    bf16x8 kv = *(const bf16x8*)(row + d0);
#pragma unroll
    for (int e = 0; e < 8; ++e) s += uv[d0 + e] * bf2f((unsigned short)kv[e]);
  }
  *outp = s;
}

// ---------------- fused relative attention (flash-style, barrier-free) ----------------
__global__ __launch_bounds__(256) void k_attn(const unsigned short* __restrict__ qh,
                                              const unsigned short* __restrict__ kh,
                                              const unsigned short* __restrict__ vt,
                                              const unsigned short* __restrict__ rh,
                                              const float* __restrict__ biask,
                                              const float* __restrict__ biasr,
                                              unsigned short* __restrict__ attnb) {
  __shared__ float ring[4][16][128];          // per-wave E ring: rows x (mod-128 p)
  __shared__ unsigned short pls[4][16 * 64];  // per-wave P tile, XOR-swizzled 128B rows

  const int tid = threadIdx.x;
  const int w = tid >> 6, l = tid & 63;
  const int l15 = l & 15, lg = l >> 4;
  const int bh = blockIdx.y, b = bh >> 4, h = bh & (H_ - 1);
  const int i0 = blockIdx.x * 64;
  const int iw = i0 + w * 16;  // wave's first q row

  // Q fragments (held in regs whole kernel): rows iw+l15, k = lg*8 (+32)
  const unsigned short* qrow = qh + ((int64_t)bh * Q_ + iw + l15) * DK_ + lg * 8;
  const bf16x8 aq0 = ld8(qrow), aq1 = ld8(qrow + 32);

  const unsigned short* kbase = kh + (int64_t)bh * K_ * DK_;
  const unsigned short* rbase = rh + (int64_t)h * K_ * DK_;
  const unsigned short* vbase = vt + (int64_t)bh * DK_ * K_;
  const float* bkp = biask + bh * K_;
  const float* brp = biasr + h * K_;

  const f32x4 zero = {0.f, 0.f, 0.f, 0.f};
  float mrow[4], lsum[4];
  f32x4 oacc[4];
#pragma unroll
  for (int r = 0; r < 4; ++r) { mrow[r] = -1e30f; lsum[r] = 0.f; }
#pragma unroll
  for (int c = 0; c < 4; ++c) oacc[c] = zero;

  // compute E[rows][pE..pE+63] into the ring (E = q . r_p)
  auto epass = [&](int pE) {
#pragma unroll
    for (int cf = 0; cf < 4; ++cf) {
      int p = pE + cf * 16 + l15;
      int pc = p < K_ ? p : (K_ - 1);
      const unsigned short* rrow = rbase + (int64_t)pc * DK_ + lg * 8;
      f32x4 e = zero;
      e = __builtin_amdgcn_mfma_f32_16x16x32_bf16(aq0, ld8(rrow), e, 0, 0, 0);
      e = __builtin_amdgcn_mfma_f32_16x16x32_bf16(aq1, ld8(rrow + 32), e, 0, 0, 0);
      int pcol = p & 127;
#pragma unroll
      for (int r = 0; r < 4; ++r) ring[w][lg * 4 + r][pcol] = e[r];
    }
  };

  epass(Q_ - 64 - i0);  // prologue: left half of first window

  const int njt = (i0 / 64 + 17) < 32 ? (i0 / 64 + 17) : 32;
  char* pw = (char*)&pls[w][0];

  for (int jt = 0; jt < njt; ++jt) {
    const int j0 = jt * 64;
    epass(j0 + Q_ - i0);  // 64 new p-columns for this tile

    // AC = q . k_j
    f32x4 sc[4];
#pragma unroll
    for (int cf = 0; cf < 4; ++cf) {
      int j = j0 + cf * 16 + l15;
      const unsigned short* krow = kbase + (int64_t)j * DK_ + lg * 8;
      f32x4 s = zero;
      s = __builtin_amdgcn_mfma_f32_16x16x32_bf16(aq0, ld8(krow), s, 0, 0, 0);
      s = __builtin_amdgcn_mfma_f32_16x16x32_bf16(aq1, ld8(krow + 32), s, 0, 0, 0);
      sc[cf] = s;
    }

    // S = (AC + u.k + E[p] + v.r_p) / 8, masked
#pragma unroll
    for (int cf = 0; cf < 4; ++cf) {
      int j = j0 + cf * 16 + l15;
      float bk = bkp[j];
#pragma unroll
      for (int r = 0; r < 4; ++r) {
        int il = lg * 4 + r;
        int ig = iw + il;
        int p = j + Q_ - 1 - ig;
        int pc = p < K_ ? p : (K_ - 1);
        float s = (sc[cf][r] + bk + ring[w][il][p & 127] + brp[pc]) * 0.125f;
        sc[cf][r] = (j <= ig + MM_) ? s : -1e30f;
      }
    }

    // online softmax (rows live in 16-lane groups -> shfl-only reduce)
#pragma unroll
    for (int r = 0; r < 4; ++r) {
      float tm = fmaxf(fmaxf(sc[0][r], sc[1][r]), fmaxf(sc[2][r], sc[3][r]));
      tm = fmaxf(tm, __shfl_xor(tm, 1));
      tm = fmaxf(tm, __shfl_xor(tm, 2));
      tm = fmaxf(tm, __shfl_xor(tm, 4));
      tm = fmaxf(tm, __shfl_xor(tm, 8));
      float mnew = fmaxf(mrow[r], tm);
      float alpha = __expf(mrow[r] - mnew);
      mrow[r] = mnew;
      float rs = 0.f;
#pragma unroll
      for (int cf = 0; cf < 4; ++cf) {
        float pv = __expf(sc[cf][r] - mnew);
        sc[cf][r] = pv;
        rs += pv;
      }
      rs += __shfl_xor(rs, 1);
      rs += __shfl_xor(rs, 2);
      rs += __shfl_xor(rs, 4);
      rs += __shfl_xor(rs, 8);
      lsum[r] = lsum[r] * alpha + rs;
#pragma unroll
      for (int cf = 0; cf < 4; ++cf) oacc[cf][r] *= alpha;
    }

    // P -> LDS (bf16, swizzled), then PV
#pragma unroll
    for (int cf = 0; cf < 4; ++cf) {
#pragma unroll
      for (int r = 0; r < 4; ++r) {
        int il = lg * 4 + r;
        int off = il * 128 + ((((cf * 16 + l15) * 2)) ^ ((il & 7) << 4));
        *(unsigned short*)(pw + off) = f2bf(sc[cf][r]);
      }
    }
#pragma unroll
    for (int kf = 0; kf < 2; ++kf) {
      int off = l15 * 128 + (((kf * 32 + lg * 8) * 2) ^ ((l15 & 7) << 4));
      bf16x8 pa = *(const bf16x8*)(pw + off);
#pragma unroll
      for (int cf = 0; cf < 4; ++cf) {
        const unsigned short* vrow =
            vbase + (int64_t)(cf * 16 + l15) * K_ + j0 + kf * 32 + lg * 8;
        oacc[cf] = __builtin_amdgcn_mfma_f32_16x16x32_bf16(pa, ld8(vrow), oacc[cf], 0, 0, 0);
      }
    }
  }

#pragma unroll
  for (int cf = 0; cf < 4; ++cf) {
#pragma unroll
    for (int r = 0; r < 4; ++r) {
      int ig = iw + lg * 4 + r;
      float o = oacc[cf][r] / lsum[r];
      attnb[((int64_t)b * Q_ + ig) * D_ + h * 64 + cf * 16 + l15] = f2bf(o);
    }
  }
}

// ---------------- launcher ----------------
extern "C" void kernel_launch(void* const* d_in, const int* in_sizes, int n_in, void* d_out,
                              int out_size, void* d_ws, size_t ws_size, hipStream_t stream) {
  const float* xin = (const float*)d_in[0];
  const float* xmem = (const float*)d_in[1];
  const float* rin = (const float*)d_in[2];
  const float* W = (const float*)d_in[3];
  const float* Wr = (const float*)d_in[4];
  const float* Wo = (const float*)d_in[5];
  const float* u = (const float*)d_in[6];
  const float* v = (const float*)d_in[7];
  float* out = (float*)d_out;

  char* ws = (char*)d_ws;
  size_t off = 0;
  auto take = [&](size_t n) {
    char* p = ws + off;
    off += (n + 255) & ~(size_t)255;
    return p;
  };
  unsigned short* Wt = (unsigned short*)take((size_t)D3_ * D_ * 2);
  unsigned short* Wrt = (unsigned short*)take((size_t)D_ * D_ * 2);
  unsigned short* Wot = (unsigned short*)take((size_t)D_ * D_ * 2);
  unsigned short* xcat = (unsigned short*)take((size_t)B_ * K_ * D_ * 2);
  unsigned short* rbf = (unsigned short*)take((size_t)K_ * D_ * 2);
  unsigned short* qh = (unsigned short*)take((size_t)B_ * H_ * Q_ * DK_ * 2);
  unsigned short* kh = (unsigned short*)take((size_t)B_ * H_ * K_ * DK_ * 2);
  unsigned short* vt = (unsigned short*)take((size_t)B_ * H_ * DK_ * K_ * 2);
  unsigned short* rh = (unsigned short*)take((size_t)H_ * K_ * DK_ * 2);
  float* biask = (float*)take((size_t)B_ * H_ * K_ * 4);
  float* biasr = (float*)take((size_t)H_ * K_ * 4);
  unsigned short* attnb = rbf;  // overlay: rbf dead after r-GEMM, same size (4 MiB)

  if (ws_size < off) return;  // insufficient workspace -> fail loudly via absmax

  {
    int64_t total = (int64_t)B_ * K_ * D_ / 4 + (int64_t)K_ * D_ / 4;
    k_convert<<<dim3((unsigned)((total + 255) / 256)), 256, 0, stream>>>(xin, xmem, rin, xcat, rbf);
  }
  k_transw<<<dim3(D3_ / 32, D_ / 32), 256, 0, stream>>>(W, Wt, D_, D3_);
  k_transw<<<dim3(D_ / 32, D_ / 32), 256, 0, stream>>>(Wr, Wrt, D_, D_);
  k_transw<<<dim3(D_ / 32, D_ / 32), 256, 0, stream>>>(Wo, Wot, D_, D_);

  k_gemm128<0><<<dim3((B_ * K_) / 128, D3_ / 128), 256, 0, stream>>>(xcat, Wt, qh, kh, vt, nullptr);
  k_gemm128<1><<<dim3(K_ / 128, D_ / 128), 256, 0, stream>>>(rbf, Wrt, rh, nullptr, nullptr, nullptr);

  k_bias<<<dim3((B_ * H_ * K_ + H_ * K_ + 255) / 256), 256, 0, stream>>>(kh, rh, u, v, biask, biasr);

  k_attn<<<dim3(Q_ / 64, B_ * H_), 256, 0, stream>>>(qh, kh, vt, rh, biask, biasr, attnb);

  k_gemm128<2><<<dim3((B_ * Q_) / 128, D_ / 128), 256, 0, stream>>>(attnb, Wot, nullptr, nullptr, nullptr, out);
}

// Round 5
// 384.441 us; speedup vs baseline: 1.2514x; 1.2514x over previous
//
#include <hip/hip_runtime.h>
#include <hip/hip_bf16.h>

#define DI __device__ __forceinline__

typedef __attribute__((ext_vector_type(8))) short bf16x8;
typedef __attribute__((ext_vector_type(4))) short bf16x4;
typedef __attribute__((ext_vector_type(4))) float f32x4;

static constexpr int B_ = 2, Q_ = 1024, MM_ = 1024, K_ = 2048, D_ = 1024, H_ = 16, DK_ = 64, D3_ = 3072;

DI unsigned short f2bf(float f) {
  unsigned int x = __builtin_bit_cast(unsigned int, f);
  x += 0x7fffu + ((x >> 16) & 1u);
  return (unsigned short)(x >> 16);
}
DI float bf2f(unsigned short u) {
  unsigned int x = ((unsigned int)u) << 16;
  return __builtin_bit_cast(float, x);
}
DI void gload_lds16(const void* g, void* l) {
  __builtin_amdgcn_global_load_lds((const __attribute__((address_space(1))) unsigned int*)g,
                                   (__attribute__((address_space(3))) unsigned int*)l, 16, 0, 0);
}
DI bf16x8 ld8(const unsigned short* p) { return *(const bf16x8*)p; }

// ---------------- prep: convert inputs to bf16 ----------------
__global__ __launch_bounds__(256) void k_convert(const float* __restrict__ xin,
                                                 const float* __restrict__ xmem,
                                                 const float* __restrict__ rin,
                                                 unsigned short* __restrict__ xcat,
                                                 unsigned short* __restrict__ rbf) {
  const int64_t nx = (int64_t)B_ * K_ * D_ / 4;
  const int64_t nr = (int64_t)K_ * D_ / 4;
  int64_t idx = (int64_t)blockIdx.x * 256 + threadIdx.x;
  const float* src;
  unsigned short* dst;
  if (idx < nx) {
    int64_t e = idx * 4;
    int d = (int)(e & (D_ - 1));
    int64_t t = e >> 10;
    int kpos = (int)(t & (K_ - 1));
    int b = (int)(t >> 11);
    src = (kpos < MM_) ? xmem + ((int64_t)b * MM_ + kpos) * D_ + d
                       : xin + ((int64_t)b * Q_ + (kpos - MM_)) * D_ + d;
    dst = xcat + e;
  } else if (idx < nx + nr) {
    int64_t e = (idx - nx) * 4;
    src = rin + e;
    dst = rbf + e;
  } else {
    return;
  }
  float4 fv = *(const float4*)src;
  dst[0] = f2bf(fv.x); dst[1] = f2bf(fv.y); dst[2] = f2bf(fv.z); dst[3] = f2bf(fv.w);
}

// ---------------- prep: transpose+convert a weight (R x C f32 -> C x R bf16) ----
__global__ __launch_bounds__(256) void k_transw(const float* __restrict__ src,
                                                unsigned short* __restrict__ dst, int R, int C) {
  __shared__ float t[32][33];
  const int c0 = blockIdx.x * 32, r0 = blockIdx.y * 32;
  const int tx = threadIdx.x & 31, ty = threadIdx.x >> 5;
#pragma unroll
  for (int i = 0; i < 32; i += 8) t[ty + i][tx] = src[(int64_t)(r0 + ty + i) * C + c0 + tx];
  __syncthreads();
#pragma unroll
  for (int i = 0; i < 32; i += 8)
    dst[(int64_t)(c0 + ty + i) * R + r0 + tx] = f2bf(t[tx][ty + i]);
}

// ---------------- 128x128 bf16 GEMM: C = A(Mx1024) * Bw(Nx1024)^T ----------------
template <int EPI>
__global__ __launch_bounds__(256) void k_gemm128(const unsigned short* __restrict__ A,
                                                 const unsigned short* __restrict__ Bw,
                                                 unsigned short* __restrict__ o0,
                                                 unsigned short* __restrict__ o1,
                                                 unsigned short* __restrict__ o2,
                                                 float* __restrict__ of) {
  __shared__ unsigned short sA[2][128 * 32];
  __shared__ unsigned short sB[2][128 * 32];
  const int tid = threadIdx.x, w = tid >> 6, l = tid & 63;
  const int l15 = l & 15, lg = l >> 4;
  const int bm = blockIdx.x, bn = blockIdx.y;
  const int qr = (w >> 1) * 64, qc = (w & 1) * 64;
  const int srow = w * 16 + (l >> 2);
  const int skel = (l & 3) * 8;

  const unsigned short* Ab = A + (int64_t)(bm * 128) * D_;
  const unsigned short* Bb = Bw + (int64_t)(bn * 128) * D_;

  const f32x4 zero = {0.f, 0.f, 0.f, 0.f};
  f32x4 acc[4][4];
#pragma unroll
  for (int i = 0; i < 4; ++i)
#pragma unroll
    for (int j = 0; j < 4; ++j) acc[i][j] = zero;

  auto stage = [&](int buf, int kt) {
    int kb = kt * 32 + skel;
#pragma unroll
    for (int rr = 0; rr < 2; ++rr) {
      int row = rr * 64 + srow;
      gload_lds16(Ab + (int64_t)row * D_ + kb, &sA[buf][row * 32 + skel]);
      gload_lds16(Bb + (int64_t)row * D_ + kb, &sB[buf][row * 32 + skel]);
    }
  };

  stage(0, 0);
  __syncthreads();
  int buf = 0;
  const int nkt = D_ / 32;
  for (int kt = 0; kt < nkt; ++kt) {
    if (kt + 1 < nkt) stage(buf ^ 1, kt + 1);
    bf16x8 af[4], bfr[4];
#pragma unroll
    for (int i = 0; i < 4; ++i) {
      af[i] = *(const bf16x8*)&sA[buf][(qr + i * 16 + l15) * 32 + lg * 8];
      bfr[i] = *(const bf16x8*)&sB[buf][(qc + i * 16 + l15) * 32 + lg * 8];
    }
#pragma unroll
    for (int i = 0; i < 4; ++i)
#pragma unroll
      for (int j = 0; j < 4; ++j)
        acc[i][j] = __builtin_amdgcn_mfma_f32_16x16x32_bf16(af[i], bfr[j], acc[i][j], 0, 0, 0);
    __syncthreads();
    buf ^= 1;
  }

#pragma unroll
  for (int i = 0; i < 4; ++i) {
#pragma unroll
    for (int j = 0; j < 4; ++j) {
      const int gr0 = bm * 128 + qr + i * 16 + lg * 4;
      const int gc = bn * 128 + qc + j * 16 + l15;
      if constexpr (EPI == 2) {
#pragma unroll
        for (int r = 0; r < 4; ++r) of[(int64_t)(gr0 + r) * D_ + gc] = acc[i][j][r];
      } else if constexpr (EPI == 1) {
        const int hh = gc >> 6, d = gc & 63;
#pragma unroll
        for (int r = 0; r < 4; ++r)
          o0[((int64_t)hh * K_ + gr0 + r) * DK_ + d] = f2bf(acc[i][j][r]);
      } else {
        const int sel = gc >> 6, d = gc & 63;
        const int ty = sel >> 4, hh = sel & 15;
        const int bb = gr0 >> 11, kp0 = gr0 & (K_ - 1);
        if (ty == 0) {
#pragma unroll
          for (int r = 0; r < 4; ++r) {
            int kp = kp0 + r;
            if (kp >= MM_)
              o0[(((int64_t)bb * H_ + hh) * Q_ + (kp - MM_)) * DK_ + d] = f2bf(acc[i][j][r]);
          }
        } else if (ty == 1) {
#pragma unroll
          for (int r = 0; r < 4; ++r)
            o1[(((int64_t)bb * H_ + hh) * K_ + kp0 + r) * DK_ + d] = f2bf(acc[i][j][r]);
        } else {
          bf16x4 tv;
#pragma unroll
          for (int r = 0; r < 4; ++r) tv[r] = (short)f2bf(acc[i][j][r]);
          *(bf16x4*)(o2 + (((int64_t)bb * H_ + hh) * DK_ + d) * K_ + kp0) = tv;
        }
      }
    }
  }
}

// ---------------- rank-1 biases: u.k_j and v.r_p ----------------
__global__ __launch_bounds__(256) void k_bias(const unsigned short* __restrict__ kh,
                                              const unsigned short* __restrict__ rh,
                                              const float* __restrict__ u,
                                              const float* __restrict__ v,
                                              float* __restrict__ biask,
                                              float* __restrict__ biasr) {
  int gid = blockIdx.x * 256 + threadIdx.x;
  const int nk = B_ * H_ * K_;
  const unsigned short* row;
  const float* uv;
  float* outp;
  if (gid < nk) {
    int h = (gid >> 11) & (H_ - 1);
    row = kh + (int64_t)gid * DK_;
    uv = u + h * DK_;
    outp = biask + gid;
  } else if (gid < nk + H_ * K_) {
    int g = gid - nk;
    int h = g >> 11;
    row = rh + (int64_t)g * DK_;
    uv = v + h * DK_;
    outp = biasr + g;
  } else {
    return;
  }
  float s = 0.f;
#pragma unroll
  for (int d0 = 0; d0 < DK_; d0 += 8) {
    bf16x8 kv = *(const bf16x8*)(row + d0);
#pragma unroll
    for (int e = 0; e < 8; ++e) s += uv[d0 + e] * bf2f((unsigned short)kv[e]);
  }
  *outp = s;
}

// ring column swizzle: XOR by row-group (lg = il>>2) * 8 -> write conflicts 4-way -> 2-way (free)
DI int rcol(int il, int p) { return (p & 127) ^ ((il >> 2) << 3); }

// ---------------- fused relative attention, KV-split x2, partial outputs ----------------
__global__ __launch_bounds__(256, 4) void k_attn(const unsigned short* __restrict__ qh,
                                                 const unsigned short* __restrict__ kh,
                                                 const unsigned short* __restrict__ vt,
                                                 const unsigned short* __restrict__ rh,
                                                 const float* __restrict__ biask,
                                                 const float* __restrict__ biasr,
                                                 float* __restrict__ P0,
                                                 float* __restrict__ P1,
                                                 float* __restrict__ mlbuf) {
  __shared__ float ring[4][16][128];          // per-wave E ring (v.r folded in)
  __shared__ unsigned short pls[4][16 * 64];  // per-wave P tile, XOR-swizzled 128B rows

  const int tid = threadIdx.x;
  const int w = tid >> 6, l = tid & 63;
  const int l15 = l & 15, lg = l >> 4;
  const int bh = blockIdx.y, b = bh >> 4, h = bh & (H_ - 1);
  const int i0 = blockIdx.x * 64;
  const int chunk = blockIdx.z;
  const int iw = i0 + w * 16;

  const unsigned short* qrow = qh + ((int64_t)bh * Q_ + iw + l15) * DK_ + lg * 8;
  const bf16x8 aq0 = ld8(qrow), aq1 = ld8(qrow + 32);

  const unsigned short* kbase = kh + (int64_t)bh * K_ * DK_;
  const unsigned short* rbase = rh + (int64_t)h * K_ * DK_;
  const unsigned short* vbase = vt + (int64_t)bh * DK_ * K_;
  const float* bkp = biask + bh * K_;
  const float* brp = biasr + h * K_;

  float mrow[4], lsum[4];
  f32x4 oacc[4];
#pragma unroll
  for (int r = 0; r < 4; ++r) { mrow[r] = -1e30f; lsum[r] = 0.f; }
#pragma unroll
  for (int c = 0; c < 4; ++c) oacc[c] = f32x4{0.f, 0.f, 0.f, 0.f};

  // E ring fill: e = q.r_p + v.r_p (bias via MFMA C-init), batched loads
  auto epass = [&](int pE) {
    bf16x8 rf[8];
    float br[4];
    int pcs[4];
#pragma unroll
    for (int cf = 0; cf < 4; ++cf) {
      int p = pE + cf * 16 + l15;
      int pc = p < K_ ? p : (K_ - 1);
      pcs[cf] = p;
      const unsigned short* rr = rbase + (int64_t)pc * DK_ + lg * 8;
      rf[2 * cf] = ld8(rr);
      rf[2 * cf + 1] = ld8(rr + 32);
      br[cf] = brp[pc];
    }
#pragma unroll
    for (int cf = 0; cf < 4; ++cf) {
      f32x4 e = {br[cf], br[cf], br[cf], br[cf]};
      e = __builtin_amdgcn_mfma_f32_16x16x32_bf16(aq0, rf[2 * cf], e, 0, 0, 0);
      e = __builtin_amdgcn_mfma_f32_16x16x32_bf16(aq1, rf[2 * cf + 1], e, 0, 0, 0);
#pragma unroll
      for (int r = 0; r < 4; ++r) {
        int il = lg * 4 + r;
        ring[w][il][rcol(il, pcs[cf])] = e[r];
      }
    }
  };

  const int njt = i0 / 64 + 17;  // 17..32
  const int half = njt >> 1;
  const int jt_lo = chunk ? half : 0;
  const int jt_hi = chunk ? njt : half;

  epass(jt_lo * 64 + (Q_ - 64 - i0));  // prologue: left half of first window

  char* pw = (char*)&pls[w][0];

  for (int jt = jt_lo; jt < jt_hi; ++jt) {
    const int j0 = jt * 64;
    epass(j0 + Q_ - i0);  // 64 new p-columns

    // AC = q.k_j + u.k_j (bias via C-init), batched loads
    bf16x8 kf[8];
    float bk[4];
#pragma unroll
    for (int cf = 0; cf < 4; ++cf) {
      int j = j0 + cf * 16 + l15;
      const unsigned short* kr = kbase + (int64_t)j * DK_ + lg * 8;
      kf[2 * cf] = ld8(kr);
      kf[2 * cf + 1] = ld8(kr + 32);
      bk[cf] = bkp[j];
    }
    f32x4 sc[4];
#pragma unroll
    for (int cf = 0; cf < 4; ++cf) {
      f32x4 s = {bk[cf], bk[cf], bk[cf], bk[cf]};
      s = __builtin_amdgcn_mfma_f32_16x16x32_bf16(aq0, kf[2 * cf], s, 0, 0, 0);
      s = __builtin_amdgcn_mfma_f32_16x16x32_bf16(aq1, kf[2 * cf + 1], s, 0, 0, 0);
      sc[cf] = s;
    }

    // S = (AC' + ring)/8; mask only the final tile
#pragma unroll
    for (int cf = 0; cf < 4; ++cf) {
      int j = j0 + cf * 16 + l15;
#pragma unroll
      for (int r = 0; r < 4; ++r) {
        int il = lg * 4 + r;
        int p = j + Q_ - 1 - (iw + il);
        sc[cf][r] = (sc[cf][r] + ring[w][il][rcol(il, p)]) * 0.125f;
      }
    }
    if (jt == njt - 1) {
#pragma unroll
      for (int cf = 0; cf < 4; ++cf) {
        int j = j0 + cf * 16 + l15;
#pragma unroll
        for (int r = 0; r < 4; ++r) {
          int ig = iw + lg * 4 + r;
          if (j > ig + MM_) sc[cf][r] = -1e30f;
        }
      }
    }

    // online softmax (rows in 16-lane groups)
#pragma unroll
    for (int r = 0; r < 4; ++r) {
      float tm = fmaxf(fmaxf(sc[0][r], sc[1][r]), fmaxf(sc[2][r], sc[3][r]));
      tm = fmaxf(tm, __shfl_xor(tm, 1));
      tm = fmaxf(tm, __shfl_xor(tm, 2));
      tm = fmaxf(tm, __shfl_xor(tm, 4));
      tm = fmaxf(tm, __shfl_xor(tm, 8));
      float mnew = fmaxf(mrow[r], tm);
      float alpha = __expf(mrow[r] - mnew);
      mrow[r] = mnew;
      float rs = 0.f;
#pragma unroll
      for (int cf = 0; cf < 4; ++cf) {
        float pv = __expf(sc[cf][r] - mnew);
        sc[cf][r] = pv;
        rs += pv;
      }
      rs += __shfl_xor(rs, 1);
      rs += __shfl_xor(rs, 2);
      rs += __shfl_xor(rs, 4);
      rs += __shfl_xor(rs, 8);
      lsum[r] = lsum[r] * alpha + rs;
#pragma unroll
      for (int cf = 0; cf < 4; ++cf) oacc[cf][r] *= alpha;
    }

    // P -> LDS (bf16, swizzled)
#pragma unroll
    for (int cf = 0; cf < 4; ++cf) {
#pragma unroll
      for (int r = 0; r < 4; ++r) {
        int il = lg * 4 + r;
        int off = il * 128 + ((((cf * 16 + l15) * 2)) ^ ((il & 7) << 4));
        *(unsigned short*)(pw + off) = f2bf(sc[cf][r]);
      }
    }
    // V loads batched, then P readback, then PV MFMAs
    bf16x8 vf[8];
#pragma unroll
    for (int kf2 = 0; kf2 < 2; ++kf2)
#pragma unroll
      for (int cf = 0; cf < 4; ++cf)
        vf[kf2 * 4 + cf] = ld8(vbase + (int64_t)(cf * 16 + l15) * K_ + j0 + kf2 * 32 + lg * 8);
#pragma unroll
    for (int kf2 = 0; kf2 < 2; ++kf2) {
      int off = l15 * 128 + (((kf2 * 32 + lg * 8) * 2) ^ ((l15 & 7) << 4));
      bf16x8 pa = *(const bf16x8*)(pw + off);
#pragma unroll
      for (int cf = 0; cf < 4; ++cf)
        oacc[cf] = __builtin_amdgcn_mfma_f32_16x16x32_bf16(pa, vf[kf2 * 4 + cf], oacc[cf], 0, 0, 0);
    }
  }

  // partial write-out: raw O (f32) + m,l
  float* Pc = chunk ? P1 : P0;
#pragma unroll
  for (int cf = 0; cf < 4; ++cf) {
#pragma unroll
    for (int r = 0; r < 4; ++r) {
      int ig = iw + lg * 4 + r;
      Pc[((int64_t)((bh << 10) + ig) << 6) + cf * 16 + l15] = oacc[cf][r];
    }
  }
  if (l15 == 0) {
#pragma unroll
    for (int r = 0; r < 4; ++r) {
      int ig = iw + lg * 4 + r;
      int mi = ((((chunk << 5) + bh) << 10) + ig) << 1;
      mlbuf[mi] = mrow[r];
      mlbuf[mi + 1] = lsum[r];
    }
  }
}

// ---------------- combine partials -> attnb (bf16) ----------------
__global__ __launch_bounds__(256) void k_combine(const float* __restrict__ P0,
                                                 const float* __restrict__ P1,
                                                 const float* __restrict__ mlbuf,
                                                 unsigned short* __restrict__ attnb) {
  int t = blockIdx.x * 256 + threadIdx.x;  // over 32768 rows x 64 cols
  int row = t >> 6, d = t & 63;
  int bh = row >> 10, i = row & (Q_ - 1), b = bh >> 4, h = bh & 15;
  int mi0 = ((bh << 10) + i) << 1;
  int mi1 = (((32 + bh) << 10) + i) << 1;
  float m0 = mlbuf[mi0], l0 = mlbuf[mi0 + 1];
  float m1 = mlbuf[mi1], l1 = mlbuf[mi1 + 1];
  float m = fmaxf(m0, m1);
  float a0 = __expf(m0 - m), a1 = __expf(m1 - m);
  float inv = 1.f / (a0 * l0 + a1 * l1);
  float o = (a0 * P0[t] + a1 * P1[t]) * inv;
  attnb[((int64_t)b * Q_ + i) * D_ + h * 64 + d] = f2bf(o);
}

// ---------------- launcher ----------------
extern "C" void kernel_launch(void* const* d_in, const int* in_sizes, int n_in, void* d_out,
                              int out_size, void* d_ws, size_t ws_size, hipStream_t stream) {
  const float* xin = (const float*)d_in[0];
  const float* xmem = (const float*)d_in[1];
  const float* rin = (const float*)d_in[2];
  const float* W = (const float*)d_in[3];
  const float* Wr = (const float*)d_in[4];
  const float* Wo = (const float*)d_in[5];
  const float* u = (const float*)d_in[6];
  const float* v = (const float*)d_in[7];
  float* out = (float*)d_out;

  char* ws = (char*)d_ws;
  size_t off = 0;
  auto take = [&](size_t n) {
    char* p = ws + off;
    off += (n + 255) & ~(size_t)255;
    return p;
  };
  unsigned short* Wt = (unsigned short*)take((size_t)D3_ * D_ * 2);   // 6 MiB  (dead after QKV GEMM)
  unsigned short* Wrt = (unsigned short*)take((size_t)D_ * D_ * 2);   // 2 MiB  (dead after r GEMM)
  unsigned short* Wot = (unsigned short*)take((size_t)D_ * D_ * 2);
  unsigned short* xcat = (unsigned short*)take((size_t)B_ * K_ * D_ * 2);  // 8 MiB (dead after QKV GEMM)
  unsigned short* rbf = (unsigned short*)take((size_t)K_ * D_ * 2);
  unsigned short* qh = (unsigned short*)take((size_t)B_ * H_ * Q_ * DK_ * 2);
  unsigned short* kh = (unsigned short*)take((size_t)B_ * H_ * K_ * DK_ * 2);
  unsigned short* vt = (unsigned short*)take((size_t)B_ * H_ * DK_ * K_ * 2);
  unsigned short* rh = (unsigned short*)take((size_t)H_ * K_ * DK_ * 2);
  float* biask = (float*)take((size_t)B_ * H_ * K_ * 4);
  float* biasr = (float*)take((size_t)H_ * K_ * 4);
  float* mlbuf = (float*)take((size_t)2 * 32 * Q_ * 2 * 4);  // 512 KiB (m,l per chunk/row)
  unsigned short* attnb = rbf;        // overlay: rbf dead after r-GEMM
  float* Pp0 = (float*)xcat;          // overlay: 8 MiB, chunk-0 raw O
  float* Pp1 = (float*)ws;            // overlay: Wt+Wrt = exactly 8 MiB, chunk-1 raw O

  if (ws_size < off) return;

  {
    int64_t total = (int64_t)B_ * K_ * D_ / 4 + (int64_t)K_ * D_ / 4;
    k_convert<<<dim3((unsigned)((total + 255) / 256)), 256, 0, stream>>>(xin, xmem, rin, xcat, rbf);
  }
  k_transw<<<dim3(D3_ / 32, D_ / 32), 256, 0, stream>>>(W, Wt, D_, D3_);
  k_transw<<<dim3(D_ / 32, D_ / 32), 256, 0, stream>>>(Wr, Wrt, D_, D_);
  k_transw<<<dim3(D_ / 32, D_ / 32), 256, 0, stream>>>(Wo, Wot, D_, D_);

  k_gemm128<0><<<dim3((B_ * K_) / 128, D3_ / 128), 256, 0, stream>>>(xcat, Wt, qh, kh, vt, nullptr);
  k_gemm128<1><<<dim3(K_ / 128, D_ / 128), 256, 0, stream>>>(rbf, Wrt, rh, nullptr, nullptr, nullptr);

  k_bias<<<dim3((B_ * H_ * K_ + H_ * K_ + 255) / 256), 256, 0, stream>>>(kh, rh, u, v, biask, biasr);

  k_attn<<<dim3(Q_ / 64, B_ * H_, 2), 256, 0, stream>>>(qh, kh, vt, rh, biask, biasr, Pp0, Pp1, mlbuf);
  k_combine<<<dim3((B_ * H_ * Q_ * DK_) / 256), 256, 0, stream>>>(Pp0, Pp1, mlbuf, attnb);

  k_gemm128<2><<<dim3((B_ * Q_) / 128, D_ / 128), 256, 0, stream>>>(attnb, Wot, nullptr, nullptr, nullptr, out);
}

// Round 6
// 377.647 us; speedup vs baseline: 1.2739x; 1.0180x over previous
//
#include <hip/hip_runtime.h>
#include <hip/hip_bf16.h>

#define DI __device__ __forceinline__

typedef __attribute__((ext_vector_type(8))) short bf16x8;
typedef __attribute__((ext_vector_type(4))) short bf16x4;
typedef __attribute__((ext_vector_type(4))) float f32x4;

static constexpr int B_ = 2, Q_ = 1024, MM_ = 1024, K_ = 2048, D_ = 1024, H_ = 16, DK_ = 64, D3_ = 3072;

DI unsigned short f2bf(float f) {
  unsigned int x = __builtin_bit_cast(unsigned int, f);
  x += 0x7fffu + ((x >> 16) & 1u);
  return (unsigned short)(x >> 16);
}
DI float bf2f(unsigned short u) {
  unsigned int x = ((unsigned int)u) << 16;
  return __builtin_bit_cast(float, x);
}
DI void gload_lds16(const void* g, void* l) {
  __builtin_amdgcn_global_load_lds((const __attribute__((address_space(1))) unsigned int*)g,
                                   (__attribute__((address_space(3))) unsigned int*)l, 16, 0, 0);
}
DI bf16x8 ld8(const unsigned short* p) { return *(const bf16x8*)p; }

// single-instruction cross-lane xor within 16-lane groups (BitMode swizzle)
#define SWZ(x, OFF) \
  __builtin_bit_cast(float, __builtin_amdgcn_ds_swizzle(__builtin_bit_cast(int, (x)), (OFF)))

// ---------------- prep: convert inputs to bf16 ----------------
__global__ __launch_bounds__(256) void k_convert(const float* __restrict__ xin,
                                                 const float* __restrict__ xmem,
                                                 const float* __restrict__ rin,
                                                 unsigned short* __restrict__ xcat,
                                                 unsigned short* __restrict__ rbf) {
  const int64_t nx = (int64_t)B_ * K_ * D_ / 4;
  const int64_t nr = (int64_t)K_ * D_ / 4;
  int64_t idx = (int64_t)blockIdx.x * 256 + threadIdx.x;
  const float* src;
  unsigned short* dst;
  if (idx < nx) {
    int64_t e = idx * 4;
    int d = (int)(e & (D_ - 1));
    int64_t t = e >> 10;
    int kpos = (int)(t & (K_ - 1));
    int b = (int)(t >> 11);
    src = (kpos < MM_) ? xmem + ((int64_t)b * MM_ + kpos) * D_ + d
                       : xin + ((int64_t)b * Q_ + (kpos - MM_)) * D_ + d;
    dst = xcat + e;
  } else if (idx < nx + nr) {
    int64_t e = (idx - nx) * 4;
    src = rin + e;
    dst = rbf + e;
  } else {
    return;
  }
  float4 fv = *(const float4*)src;
  dst[0] = f2bf(fv.x); dst[1] = f2bf(fv.y); dst[2] = f2bf(fv.z); dst[3] = f2bf(fv.w);
}

// ---------------- prep: transpose+convert a weight (R x C f32 -> C x R bf16) ----
__global__ __launch_bounds__(256) void k_transw(const float* __restrict__ src,
                                                unsigned short* __restrict__ dst, int R, int C) {
  __shared__ float t[32][33];
  const int c0 = blockIdx.x * 32, r0 = blockIdx.y * 32;
  const int tx = threadIdx.x & 31, ty = threadIdx.x >> 5;
#pragma unroll
  for (int i = 0; i < 32; i += 8) t[ty + i][tx] = src[(int64_t)(r0 + ty + i) * C + c0 + tx];
  __syncthreads();
#pragma unroll
  for (int i = 0; i < 32; i += 8)
    dst[(int64_t)(c0 + ty + i) * R + r0 + tx] = f2bf(t[tx][ty + i]);
}

// ---------------- 128x128 bf16 GEMM: C = A(Mx1024) * Bw(Nx1024)^T ----------------
template <int EPI>
__global__ __launch_bounds__(256) void k_gemm128(const unsigned short* __restrict__ A,
                                                 const unsigned short* __restrict__ Bw,
                                                 unsigned short* __restrict__ o0,
                                                 unsigned short* __restrict__ o1,
                                                 unsigned short* __restrict__ o2,
                                                 float* __restrict__ of) {
  __shared__ unsigned short sA[2][128 * 32];
  __shared__ unsigned short sB[2][128 * 32];
  const int tid = threadIdx.x, w = tid >> 6, l = tid & 63;
  const int l15 = l & 15, lg = l >> 4;
  const int bm = blockIdx.x, bn = blockIdx.y;
  const int qr = (w >> 1) * 64, qc = (w & 1) * 64;
  const int srow = w * 16 + (l >> 2);
  const int skel = (l & 3) * 8;

  const unsigned short* Ab = A + (int64_t)(bm * 128) * D_;
  const unsigned short* Bb = Bw + (int64_t)(bn * 128) * D_;

  const f32x4 zero = {0.f, 0.f, 0.f, 0.f};
  f32x4 acc[4][4];
#pragma unroll
  for (int i = 0; i < 4; ++i)
#pragma unroll
    for (int j = 0; j < 4; ++j) acc[i][j] = zero;

  auto stage = [&](int buf, int kt) {
    int kb = kt * 32 + skel;
#pragma unroll
    for (int rr = 0; rr < 2; ++rr) {
      int row = rr * 64 + srow;
      gload_lds16(Ab + (int64_t)row * D_ + kb, &sA[buf][row * 32 + skel]);
      gload_lds16(Bb + (int64_t)row * D_ + kb, &sB[buf][row * 32 + skel]);
    }
  };

  stage(0, 0);
  __syncthreads();
  int buf = 0;
  const int nkt = D_ / 32;
  for (int kt = 0; kt < nkt; ++kt) {
    if (kt + 1 < nkt) stage(buf ^ 1, kt + 1);
    bf16x8 af[4], bfr[4];
#pragma unroll
    for (int i = 0; i < 4; ++i) {
      af[i] = *(const bf16x8*)&sA[buf][(qr + i * 16 + l15) * 32 + lg * 8];
      bfr[i] = *(const bf16x8*)&sB[buf][(qc + i * 16 + l15) * 32 + lg * 8];
    }
#pragma unroll
    for (int i = 0; i < 4; ++i)
#pragma unroll
      for (int j = 0; j < 4; ++j)
        acc[i][j] = __builtin_amdgcn_mfma_f32_16x16x32_bf16(af[i], bfr[j], acc[i][j], 0, 0, 0);
    __syncthreads();
    buf ^= 1;
  }

#pragma unroll
  for (int i = 0; i < 4; ++i) {
#pragma unroll
    for (int j = 0; j < 4; ++j) {
      const int gr0 = bm * 128 + qr + i * 16 + lg * 4;
      const int gc = bn * 128 + qc + j * 16 + l15;
      if constexpr (EPI == 2) {
#pragma unroll
        for (int r = 0; r < 4; ++r) of[(int64_t)(gr0 + r) * D_ + gc] = acc[i][j][r];
      } else if constexpr (EPI == 1) {
        const int hh = gc >> 6, d = gc & 63;
#pragma unroll
        for (int r = 0; r < 4; ++r)
          o0[((int64_t)hh * K_ + gr0 + r) * DK_ + d] = f2bf(acc[i][j][r]);
      } else {
        const int sel = gc >> 6, d = gc & 63;
        const int ty = sel >> 4, hh = sel & 15;
        const int bb = gr0 >> 11, kp0 = gr0 & (K_ - 1);
        if (ty == 0) {
#pragma unroll
          for (int r = 0; r < 4; ++r) {
            int kp = kp0 + r;
            if (kp >= MM_)
              o0[(((int64_t)bb * H_ + hh) * Q_ + (kp - MM_)) * DK_ + d] = f2bf(acc[i][j][r]);
          }
        } else if (ty == 1) {
#pragma unroll
          for (int r = 0; r < 4; ++r)
            o1[(((int64_t)bb * H_ + hh) * K_ + kp0 + r) * DK_ + d] = f2bf(acc[i][j][r]);
        } else {
          bf16x4 tv;
#pragma unroll
          for (int r = 0; r < 4; ++r) tv[r] = (short)f2bf(acc[i][j][r]);
          *(bf16x4*)(o2 + (((int64_t)bb * H_ + hh) * DK_ + d) * K_ + kp0) = tv;
        }
      }
    }
  }
}

// ---------------- rank-1 biases: u.k_j and v.r_p ----------------
__global__ __launch_bounds__(256) void k_bias(const unsigned short* __restrict__ kh,
                                              const unsigned short* __restrict__ rh,
                                              const float* __restrict__ u,
                                              const float* __restrict__ v,
                                              float* __restrict__ biask,
                                              float* __restrict__ biasr) {
  int gid = blockIdx.x * 256 + threadIdx.x;
  const int nk = B_ * H_ * K_;
  const unsigned short* row;
  const float* uv;
  float* outp;
  if (gid < nk) {
    int h = (gid >> 11) & (H_ - 1);
    row = kh + (int64_t)gid * DK_;
    uv = u + h * DK_;
    outp = biask + gid;
  } else if (gid < nk + H_ * K_) {
    int g = gid - nk;
    int h = g >> 11;
    row = rh + (int64_t)g * DK_;
    uv = v + h * DK_;
    outp = biasr + g;
  } else {
    return;
  }
  float s = 0.f;
#pragma unroll
  for (int d0 = 0; d0 < DK_; d0 += 8) {
    bf16x8 kv = *(const bf16x8*)(row + d0);
#pragma unroll
    for (int e = 0; e < 8; ++e) s += uv[d0 + e] * bf2f((unsigned short)kv[e]);
  }
  *outp = s;
}

// ring column swizzle: XOR by row-group -> write conflicts 4-way -> 2-way (free)
DI int rcol(int il, int p) { return (p & 127) ^ ((il >> 2) << 3); }

// ---------------- fused relative attention, KV-split x2, batched-load tiles ----------------
__global__ __launch_bounds__(256, 2) void k_attn(const unsigned short* __restrict__ qh,
                                                 const unsigned short* __restrict__ kh,
                                                 const unsigned short* __restrict__ vt,
                                                 const unsigned short* __restrict__ rh,
                                                 const float* __restrict__ biask,
                                                 const float* __restrict__ biasr,
                                                 float* __restrict__ P0,
                                                 float* __restrict__ P1,
                                                 float* __restrict__ mlbuf) {
  __shared__ float ring[4][16][128];          // per-wave E ring (v.r folded in)
  __shared__ unsigned short pls[4][16 * 64];  // per-wave P tile, XOR-swizzled 128B rows

  const int tid = threadIdx.x;
  const int w = tid >> 6, l = tid & 63;
  const int l15 = l & 15, lg = l >> 4;
  const int bh = blockIdx.y, b = bh >> 4, h = bh & (H_ - 1);
  const int i0 = blockIdx.x * 64;
  const int chunk = blockIdx.z;
  const int iw = i0 + w * 16;

  const unsigned short* qrow = qh + ((int64_t)bh * Q_ + iw + l15) * DK_ + lg * 8;
  const bf16x8 aq0 = ld8(qrow), aq1 = ld8(qrow + 32);

  const unsigned short* kbase = kh + (int64_t)bh * K_ * DK_;
  const unsigned short* rbase = rh + (int64_t)h * K_ * DK_;
  const unsigned short* vbase = vt + (int64_t)bh * DK_ * K_;
  const float* bkp = biask + bh * K_;
  const float* brp = biasr + h * K_;

  float mrow[4], lsum[4];
  f32x4 oacc[4];
#pragma unroll
  for (int r = 0; r < 4; ++r) { mrow[r] = -1e30f; lsum[r] = 0.f; }
#pragma unroll
  for (int c = 0; c < 4; ++c) oacc[c] = f32x4{0.f, 0.f, 0.f, 0.f};

  const int njt = i0 / 64 + 17;  // 17..32
  const int half = njt >> 1;
  const int jt_lo = chunk ? half : 0;
  const int jt_hi = chunk ? njt : half;

  // prologue epass: fill left half of first window (E = q.r_p + v.r_p)
  {
    int pE = jt_lo * 64 + (Q_ - 64 - i0);
    bf16x8 rf[8];
    float br[4];
    int pcs[4];
#pragma unroll
    for (int cf = 0; cf < 4; ++cf) {
      int p = pE + cf * 16 + l15;
      int pc = p < K_ ? p : (K_ - 1);
      pcs[cf] = p;
      const unsigned short* rr = rbase + (int64_t)pc * DK_ + lg * 8;
      rf[2 * cf] = ld8(rr);
      rf[2 * cf + 1] = ld8(rr + 32);
      br[cf] = brp[pc];
    }
#pragma unroll
    for (int cf = 0; cf < 4; ++cf) {
      f32x4 e = {br[cf], br[cf], br[cf], br[cf]};
      e = __builtin_amdgcn_mfma_f32_16x16x32_bf16(aq0, rf[2 * cf], e, 0, 0, 0);
      e = __builtin_amdgcn_mfma_f32_16x16x32_bf16(aq1, rf[2 * cf + 1], e, 0, 0, 0);
#pragma unroll
      for (int r = 0; r < 4; ++r) {
        int il = lg * 4 + r;
        ring[w][il][rcol(il, pcs[cf])] = e[r];
      }
    }
  }

  char* pw = (char*)&pls[w][0];

#pragma unroll 2
  for (int jt = jt_lo; jt < jt_hi; ++jt) {
    const int j0 = jt * 64;
    const int pE = j0 + Q_ - i0;

    // ---- single batched load phase: R, K, V, biases (one latency window) ----
    bf16x8 rf[8], kf[8], vf[8];
    float br[4], bk[4];
    int pcs[4];
#pragma unroll
    for (int cf = 0; cf < 4; ++cf) {
      int p = pE + cf * 16 + l15;
      int pc = p < K_ ? p : (K_ - 1);
      pcs[cf] = p;
      const unsigned short* rr = rbase + (int64_t)pc * DK_ + lg * 8;
      rf[2 * cf] = ld8(rr);
      rf[2 * cf + 1] = ld8(rr + 32);
      br[cf] = brp[pc];
    }
#pragma unroll
    for (int cf = 0; cf < 4; ++cf) {
      int j = j0 + cf * 16 + l15;
      const unsigned short* kr = kbase + (int64_t)j * DK_ + lg * 8;
      kf[2 * cf] = ld8(kr);
      kf[2 * cf + 1] = ld8(kr + 32);
      bk[cf] = bkp[j];
    }
#pragma unroll
    for (int kf2 = 0; kf2 < 2; ++kf2)
#pragma unroll
      for (int cf = 0; cf < 4; ++cf)
        vf[kf2 * 4 + cf] = ld8(vbase + (int64_t)(cf * 16 + l15) * K_ + j0 + kf2 * 32 + lg * 8);

    // ---- epass: 64 new E cols into ring ----
#pragma unroll
    for (int cf = 0; cf < 4; ++cf) {
      f32x4 e = {br[cf], br[cf], br[cf], br[cf]};
      e = __builtin_amdgcn_mfma_f32_16x16x32_bf16(aq0, rf[2 * cf], e, 0, 0, 0);
      e = __builtin_amdgcn_mfma_f32_16x16x32_bf16(aq1, rf[2 * cf + 1], e, 0, 0, 0);
#pragma unroll
      for (int r = 0; r < 4; ++r) {
        int il = lg * 4 + r;
        ring[w][il][rcol(il, pcs[cf])] = e[r];
      }
    }

    // ---- AC = q.k_j + u.k_j (bias via C-init) ----
    f32x4 sc[4];
#pragma unroll
    for (int cf = 0; cf < 4; ++cf) {
      f32x4 s = {bk[cf], bk[cf], bk[cf], bk[cf]};
      s = __builtin_amdgcn_mfma_f32_16x16x32_bf16(aq0, kf[2 * cf], s, 0, 0, 0);
      s = __builtin_amdgcn_mfma_f32_16x16x32_bf16(aq1, kf[2 * cf + 1], s, 0, 0, 0);
      sc[cf] = s;
    }

    // ---- S = (AC' + ring)/8; mask only on the final tile ----
#pragma unroll
    for (int cf = 0; cf < 4; ++cf) {
      int j = j0 + cf * 16 + l15;
#pragma unroll
      for (int r = 0; r < 4; ++r) {
        int il = lg * 4 + r;
        int p = j + Q_ - 1 - (iw + il);
        sc[cf][r] = (sc[cf][r] + ring[w][il][rcol(il, p)]) * 0.125f;
      }
    }
    if (jt == njt - 1) {
#pragma unroll
      for (int cf = 0; cf < 4; ++cf) {
        int j = j0 + cf * 16 + l15;
#pragma unroll
        for (int r = 0; r < 4; ++r) {
          int ig = iw + lg * 4 + r;
          if (j > ig + MM_) sc[cf][r] = -1e30f;
        }
      }
    }

    // ---- online softmax (rows in 16-lane groups; ds_swizzle xor-reduce) ----
#pragma unroll
    for (int r = 0; r < 4; ++r) {
      float tm = fmaxf(fmaxf(sc[0][r], sc[1][r]), fmaxf(sc[2][r], sc[3][r]));
      tm = fmaxf(tm, SWZ(tm, 0x041F));
      tm = fmaxf(tm, SWZ(tm, 0x081F));
      tm = fmaxf(tm, SWZ(tm, 0x101F));
      tm = fmaxf(tm, SWZ(tm, 0x201F));
      float mnew = fmaxf(mrow[r], tm);
      float alpha = __expf(mrow[r] - mnew);
      mrow[r] = mnew;
      float rs = 0.f;
#pragma unroll
      for (int cf = 0; cf < 4; ++cf) {
        float pv = __expf(sc[cf][r] - mnew);
        sc[cf][r] = pv;
        rs += pv;
      }
      rs += SWZ(rs, 0x041F);
      rs += SWZ(rs, 0x081F);
      rs += SWZ(rs, 0x101F);
      rs += SWZ(rs, 0x201F);
      lsum[r] = lsum[r] * alpha + rs;
#pragma unroll
      for (int cf = 0; cf < 4; ++cf) oacc[cf][r] *= alpha;
    }

    // ---- P -> LDS (bf16, swizzled), read back as A-frags, PV MFMAs ----
#pragma unroll
    for (int cf = 0; cf < 4; ++cf) {
#pragma unroll
      for (int r = 0; r < 4; ++r) {
        int il = lg * 4 + r;
        int off = il * 128 + ((((cf * 16 + l15) * 2)) ^ ((il & 7) << 4));
        *(unsigned short*)(pw + off) = f2bf(sc[cf][r]);
      }
    }
#pragma unroll
    for (int kf2 = 0; kf2 < 2; ++kf2) {
      int off = l15 * 128 + (((kf2 * 32 + lg * 8) * 2) ^ ((l15 & 7) << 4));
      bf16x8 pa = *(const bf16x8*)(pw + off);
#pragma unroll
      for (int cf = 0; cf < 4; ++cf)
        oacc[cf] = __builtin_amdgcn_mfma_f32_16x16x32_bf16(pa, vf[kf2 * 4 + cf], oacc[cf], 0, 0, 0);
    }
  }

  // partial write-out: raw O (f32) + m,l
  float* Pc = chunk ? P1 : P0;
#pragma unroll
  for (int cf = 0; cf < 4; ++cf) {
#pragma unroll
    for (int r = 0; r < 4; ++r) {
      int ig = iw + lg * 4 + r;
      Pc[((int64_t)((bh << 10) + ig) << 6) + cf * 16 + l15] = oacc[cf][r];
    }
  }
  if (l15 == 0) {
#pragma unroll
    for (int r = 0; r < 4; ++r) {
      int ig = iw + lg * 4 + r;
      int mi = ((((chunk << 5) + bh) << 10) + ig) << 1;
      mlbuf[mi] = mrow[r];
      mlbuf[mi + 1] = lsum[r];
    }
  }
}

// ---------------- combine partials -> attnb (bf16) ----------------
__global__ __launch_bounds__(256) void k_combine(const float* __restrict__ P0,
                                                 const float* __restrict__ P1,
                                                 const float* __restrict__ mlbuf,
                                                 unsigned short* __restrict__ attnb) {
  int t = blockIdx.x * 256 + threadIdx.x;  // over 32768 rows x 64 cols
  int row = t >> 6, d = t & 63;
  int bh = row >> 10, i = row & (Q_ - 1), b = bh >> 4, h = bh & 15;
  int mi0 = ((bh << 10) + i) << 1;
  int mi1 = (((32 + bh) << 10) + i) << 1;
  float m0 = mlbuf[mi0], l0 = mlbuf[mi0 + 1];
  float m1 = mlbuf[mi1], l1 = mlbuf[mi1 + 1];
  float m = fmaxf(m0, m1);
  float a0 = __expf(m0 - m), a1 = __expf(m1 - m);
  float inv = 1.f / (a0 * l0 + a1 * l1);
  float o = (a0 * P0[t] + a1 * P1[t]) * inv;
  attnb[((int64_t)b * Q_ + i) * D_ + h * 64 + d] = f2bf(o);
}

// ---------------- launcher ----------------
extern "C" void kernel_launch(void* const* d_in, const int* in_sizes, int n_in, void* d_out,
                              int out_size, void* d_ws, size_t ws_size, hipStream_t stream) {
  const float* xin = (const float*)d_in[0];
  const float* xmem = (const float*)d_in[1];
  const float* rin = (const float*)d_in[2];
  const float* W = (const float*)d_in[3];
  const float* Wr = (const float*)d_in[4];
  const float* Wo = (const float*)d_in[5];
  const float* u = (const float*)d_in[6];
  const float* v = (const float*)d_in[7];
  float* out = (float*)d_out;

  char* ws = (char*)d_ws;
  size_t off = 0;
  auto take = [&](size_t n) {
    char* p = ws + off;
    off += (n + 255) & ~(size_t)255;
    return p;
  };
  unsigned short* Wt = (unsigned short*)take((size_t)D3_ * D_ * 2);   // 6 MiB  (dead after QKV GEMM)
  unsigned short* Wrt = (unsigned short*)take((size_t)D_ * D_ * 2);   // 2 MiB  (dead after r GEMM)
  unsigned short* Wot = (unsigned short*)take((size_t)D_ * D_ * 2);
  unsigned short* xcat = (unsigned short*)take((size_t)B_ * K_ * D_ * 2);  // 8 MiB (dead after QKV GEMM)
  unsigned short* rbf = (unsigned short*)take((size_t)K_ * D_ * 2);
  unsigned short* qh = (unsigned short*)take((size_t)B_ * H_ * Q_ * DK_ * 2);
  unsigned short* kh = (unsigned short*)take((size_t)B_ * H_ * K_ * DK_ * 2);
  unsigned short* vt = (unsigned short*)take((size_t)B_ * H_ * DK_ * K_ * 2);
  unsigned short* rh = (unsigned short*)take((size_t)H_ * K_ * DK_ * 2);
  float* biask = (float*)take((size_t)B_ * H_ * K_ * 4);
  float* biasr = (float*)take((size_t)H_ * K_ * 4);
  float* mlbuf = (float*)take((size_t)2 * 32 * Q_ * 2 * 4);  // 512 KiB (m,l per chunk/row)
  unsigned short* attnb = rbf;        // overlay: rbf dead after r-GEMM
  float* Pp0 = (float*)xcat;          // overlay: 8 MiB, chunk-0 raw O
  float* Pp1 = (float*)ws;            // overlay: Wt+Wrt = exactly 8 MiB, chunk-1 raw O

  if (ws_size < off) return;

  {
    int64_t total = (int64_t)B_ * K_ * D_ / 4 + (int64_t)K_ * D_ / 4;
    k_convert<<<dim3((unsigned)((total + 255) / 256)), 256, 0, stream>>>(xin, xmem, rin, xcat, rbf);
  }
  k_transw<<<dim3(D3_ / 32, D_ / 32), 256, 0, stream>>>(W, Wt, D_, D3_);
  k_transw<<<dim3(D_ / 32, D_ / 32), 256, 0, stream>>>(Wr, Wrt, D_, D_);
  k_transw<<<dim3(D_ / 32, D_ / 32), 256, 0, stream>>>(Wo, Wot, D_, D_);

  k_gemm128<0><<<dim3((B_ * K_) / 128, D3_ / 128), 256, 0, stream>>>(xcat, Wt, qh, kh, vt, nullptr);
  k_gemm128<1><<<dim3(K_ / 128, D_ / 128), 256, 0, stream>>>(rbf, Wrt, rh, nullptr, nullptr, nullptr);

  k_bias<<<dim3((B_ * H_ * K_ + H_ * K_ + 255) / 256), 256, 0, stream>>>(kh, rh, u, v, biask, biasr);

  k_attn<<<dim3(Q_ / 64, B_ * H_, 2), 256, 0, stream>>>(qh, kh, vt, rh, biask, biasr, Pp0, Pp1, mlbuf);
  k_combine<<<dim3((B_ * H_ * Q_ * DK_) / 256), 256, 0, stream>>>(Pp0, Pp1, mlbuf, attnb);

  k_gemm128<2><<<dim3((B_ * Q_) / 128, D_ / 128), 256, 0, stream>>>(attnb, Wot, nullptr, nullptr, nullptr, out);
}

// Round 10
// 303.830 us; speedup vs baseline: 1.5834x; 1.2430x over previous
//
#include <hip/hip_runtime.h>
#include <hip/hip_bf16.h>

#define DI __device__ __forceinline__

typedef __attribute__((ext_vector_type(8))) short bf16x8;
typedef __attribute__((ext_vector_type(4))) short bf16x4;
typedef __attribute__((ext_vector_type(4))) float f32x4;
typedef __attribute__((ext_vector_type(16))) float f32x16;

static constexpr int B_ = 2, Q_ = 1024, MM_ = 1024, K_ = 2048, D_ = 1024, H_ = 16, DK_ = 64, D3_ = 3072;

DI unsigned short f2bf(float f) {
  unsigned int x = __builtin_bit_cast(unsigned int, f);
  x += 0x7fffu + ((x >> 16) & 1u);
  return (unsigned short)(x >> 16);
}
DI void gload_lds16(const void* g, void* l) {
  __builtin_amdgcn_global_load_lds((const __attribute__((address_space(1))) unsigned int*)g,
                                   (__attribute__((address_space(3))) unsigned int*)l, 16, 0, 0);
}
DI bf16x8 ld8(const unsigned short* p) { return *(const bf16x8*)p; }
DI unsigned cvtpk(float lo, float hi) {
  unsigned r;
  asm("v_cvt_pk_bf16_f32 %0, %1, %2" : "=v"(r) : "v"(lo), "v"(hi));
  return r;
}
// v_permlane32_swap_b32 A, B  =>  A_new = [A_lo | B_lo], B_new = [A_hi | B_hi]
// ONLY safe when A and B are distinct SSA values (else regalloc may merge them).
#define PSWAP(a, b) asm("v_permlane32_swap_b32 %0, %1" : "+v"(a), "+v"(b))
DI int crow(int r, int hi) { return (r & 3) + 8 * (r >> 2) + 4 * hi; }

// ---------------- prep: convert inputs to bf16 ----------------
__global__ __launch_bounds__(256) void k_convert(const float* __restrict__ xin,
                                                 const float* __restrict__ xmem,
                                                 const float* __restrict__ rin,
                                                 unsigned short* __restrict__ xcat,
                                                 unsigned short* __restrict__ rbf) {
  const int64_t nx = (int64_t)B_ * K_ * D_ / 4;
  const int64_t nr = (int64_t)K_ * D_ / 4;
  int64_t idx = (int64_t)blockIdx.x * 256 + threadIdx.x;
  const float* src;
  unsigned short* dst;
  if (idx < nx) {
    int64_t e = idx * 4;
    int d = (int)(e & (D_ - 1));
    int64_t t = e >> 10;
    int kpos = (int)(t & (K_ - 1));
    int b = (int)(t >> 11);
    src = (kpos < MM_) ? xmem + ((int64_t)b * MM_ + kpos) * D_ + d
                       : xin + ((int64_t)b * Q_ + (kpos - MM_)) * D_ + d;
    dst = xcat + e;
  } else if (idx < nx + nr) {
    int64_t e = (idx - nx) * 4;
    src = rin + e;
    dst = rbf + e;
  } else {
    return;
  }
  float4 fv = *(const float4*)src;
  dst[0] = f2bf(fv.x); dst[1] = f2bf(fv.y); dst[2] = f2bf(fv.z); dst[3] = f2bf(fv.w);
}

// ---------------- prep: transpose+convert a weight (R x C f32 -> C x R bf16) ----
__global__ __launch_bounds__(256) void k_transw(const float* __restrict__ src,
                                                unsigned short* __restrict__ dst, int R, int C) {
  __shared__ float t[32][33];
  const int c0 = blockIdx.x * 32, r0 = blockIdx.y * 32;
  const int tx = threadIdx.x & 31, ty = threadIdx.x >> 5;
#pragma unroll
  for (int i = 0; i < 32; i += 8) t[ty + i][tx] = src[(int64_t)(r0 + ty + i) * C + c0 + tx];
  __syncthreads();
#pragma unroll
  for (int i = 0; i < 32; i += 8)
    dst[(int64_t)(c0 + ty + i) * R + r0 + tx] = f2bf(t[tx][ty + i]);
}

// ---------------- 128x128 bf16 GEMM: C = A(Mx1024) * Bw(Nx1024)^T ----------------
// EPI 0: QKV scatter (o0=qhu, o3=qhv [both (q+u|v)/8], o1=kh, o2=vt)
// EPI 1: rh scatter (o0=rh)    EPI 2: f32 out (of)
template <int EPI>
__global__ __launch_bounds__(256) void k_gemm128(const unsigned short* __restrict__ A,
                                                 const unsigned short* __restrict__ Bw,
                                                 unsigned short* __restrict__ o0,
                                                 unsigned short* __restrict__ o1,
                                                 unsigned short* __restrict__ o2,
                                                 unsigned short* __restrict__ o3,
                                                 const float* __restrict__ uvec,
                                                 const float* __restrict__ vvec,
                                                 float* __restrict__ of) {
  __shared__ unsigned short sA[2][128 * 32];
  __shared__ unsigned short sB[2][128 * 32];
  const int tid = threadIdx.x, w = tid >> 6, l = tid & 63;
  const int l15 = l & 15, lg = l >> 4;
  const int bm = blockIdx.x, bn = blockIdx.y;
  const int qr = (w >> 1) * 64, qc = (w & 1) * 64;
  const int srow = w * 16 + (l >> 2);
  const int skel = (l & 3) * 8;

  const unsigned short* Ab = A + (int64_t)(bm * 128) * D_;
  const unsigned short* Bb = Bw + (int64_t)(bn * 128) * D_;

  const f32x4 zero = {0.f, 0.f, 0.f, 0.f};
  f32x4 acc[4][4];
#pragma unroll
  for (int i = 0; i < 4; ++i)
#pragma unroll
    for (int j = 0; j < 4; ++j) acc[i][j] = zero;

  auto stage = [&](int buf, int kt) {
    int kb = kt * 32 + skel;
#pragma unroll
    for (int rr = 0; rr < 2; ++rr) {
      int row = rr * 64 + srow;
      gload_lds16(Ab + (int64_t)row * D_ + kb, &sA[buf][row * 32 + skel]);
      gload_lds16(Bb + (int64_t)row * D_ + kb, &sB[buf][row * 32 + skel]);
    }
  };

  stage(0, 0);
  __syncthreads();
  int buf = 0;
  const int nkt = D_ / 32;
  for (int kt = 0; kt < nkt; ++kt) {
    if (kt + 1 < nkt) stage(buf ^ 1, kt + 1);
    bf16x8 af[4], bfr[4];
#pragma unroll
    for (int i = 0; i < 4; ++i) {
      af[i] = *(const bf16x8*)&sA[buf][(qr + i * 16 + l15) * 32 + lg * 8];
      bfr[i] = *(const bf16x8*)&sB[buf][(qc + i * 16 + l15) * 32 + lg * 8];
    }
#pragma unroll
    for (int i = 0; i < 4; ++i)
#pragma unroll
      for (int j = 0; j < 4; ++j)
        acc[i][j] = __builtin_amdgcn_mfma_f32_16x16x32_bf16(af[i], bfr[j], acc[i][j], 0, 0, 0);
    __syncthreads();
    buf ^= 1;
  }

#pragma unroll
  for (int i = 0; i < 4; ++i) {
#pragma unroll
    for (int j = 0; j < 4; ++j) {
      const int gr0 = bm * 128 + qr + i * 16 + lg * 4;
      const int gc = bn * 128 + qc + j * 16 + l15;
      if constexpr (EPI == 2) {
#pragma unroll
        for (int r = 0; r < 4; ++r) of[(int64_t)(gr0 + r) * D_ + gc] = acc[i][j][r];
      } else if constexpr (EPI == 1) {
        const int hh = gc >> 6, d = gc & 63;
#pragma unroll
        for (int r = 0; r < 4; ++r)
          o0[((int64_t)hh * K_ + gr0 + r) * DK_ + d] = f2bf(acc[i][j][r]);
      } else {
        const int sel = gc >> 6, d = gc & 63;
        const int ty = sel >> 4, hh = sel & 15;
        const int bb = gr0 >> 11, kp0 = gr0 & (K_ - 1);
        if (ty == 0) {
          const float uu = uvec[hh * 64 + d] * 0.125f;
          const float vv = vvec[hh * 64 + d] * 0.125f;
#pragma unroll
          for (int r = 0; r < 4; ++r) {
            int kp = kp0 + r;
            if (kp >= MM_) {
              int64_t qi = ((int64_t)bb * H_ + hh) * Q_ + (kp - MM_);
              float base = acc[i][j][r] * 0.125f;
              o0[qi * DK_ + d] = f2bf(base + uu);
              o3[qi * DK_ + d] = f2bf(base + vv);
            }
          }
        } else if (ty == 1) {
#pragma unroll
          for (int r = 0; r < 4; ++r)
            o1[(((int64_t)bb * H_ + hh) * K_ + kp0 + r) * DK_ + d] = f2bf(acc[i][j][r]);
        } else {
          bf16x4 tv;
#pragma unroll
          for (int r = 0; r < 4; ++r) tv[r] = (short)f2bf(acc[i][j][r]);
          *(bf16x4*)(o2 + (((int64_t)bb * H_ + hh) * DK_ + d) * K_ + kp0) = tv;
        }
      }
    }
  }
}

// ---------------- fused relative attention: swapped-operand 32x32, in-reg softmax ----
// Each wave: 32 q-rows. S^T = mfma(K, Qu), E^T = mfma(Qv, R), O^T = mfma(V^T, P).
// Lane owns q = iw + (lane&31); cross-half combine via __shfl_xor(.,32).
__global__ __launch_bounds__(128, 2) void k_attn(const unsigned short* __restrict__ qhu,
                                                 const unsigned short* __restrict__ qhv,
                                                 const unsigned short* __restrict__ kh,
                                                 const unsigned short* __restrict__ vt,
                                                 const unsigned short* __restrict__ rh,
                                                 float* __restrict__ P0,
                                                 float* __restrict__ P1,
                                                 float* __restrict__ mlbuf) {
  __shared__ float scr[2][32 * 98];  // per-wave E scratch [q=32][p-col=96(+2)]; stride 98

  const int tid = threadIdx.x;
  const int w = tid >> 6, l = tid & 63;
  const int l31 = l & 31, hi = l >> 5;
  const int bh = blockIdx.y, h = bh & (H_ - 1);
  const int chunk = blockIdx.z;
  const int iw = blockIdx.x * 64 + w * 32;
  const int q = iw + l31;

  // Q fragments: lane&31 indexes the q-row for BOTH A- and B-operand layouts.
  const unsigned short* qub = qhu + ((int64_t)(bh * Q_ + q)) * DK_;
  const unsigned short* qvb = qhv + ((int64_t)(bh * Q_ + q)) * DK_;
  bf16x8 qu[4], qv[4];
#pragma unroll
  for (int s = 0; s < 4; ++s) {
    qu[s] = ld8(qub + s * 16 + hi * 8);
    qv[s] = ld8(qvb + s * 16 + hi * 8);
  }

  const unsigned short* kbase = kh + (int64_t)bh * K_ * DK_;
  const unsigned short* rbase = rh + (int64_t)h * K_ * DK_;
  const unsigned short* vbase = vt + (int64_t)bh * DK_ * K_;
  float* myscr = &scr[w][0];

  f32x16 o0a, o1a;
#pragma unroll
  for (int r = 0; r < 16; ++r) { o0a[r] = 0.f; o1a[r] = 0.f; }
  float mrow = -1e30f, lsum = 0.f;

  const int njt = (iw >> 6) + 17;
  const int half = njt >> 1;
  const int jt_lo = chunk ? half : 0;
  const int jt_hi = chunk ? njt : half;

  for (int jt = jt_lo; jt < jt_hi; ++jt) {
    const int j0 = jt * 64;
    const int pb = j0 + Q_ - 32 - iw;  // p window base; cols 0..95

    // ---- batched loads: K (2 ktiles x 4 dk-slices), R (3 ptiles x 4) ----
    bf16x8 kf[8], rf[12];
#pragma unroll
    for (int kt = 0; kt < 2; ++kt)
#pragma unroll
      for (int s = 0; s < 4; ++s)
        kf[kt * 4 + s] = ld8(kbase + (int64_t)(j0 + kt * 32 + l31) * DK_ + s * 16 + hi * 8);
#pragma unroll
    for (int pt = 0; pt < 3; ++pt) {
      int prow = pb + pt * 32 + l31;
      prow = prow < K_ ? prow : K_ - 1;
#pragma unroll
      for (int s = 0; s < 4; ++s)
        rf[pt * 4 + s] = ld8(rbase + (int64_t)prow * DK_ + s * 16 + hi * 8);
    }

    // ---- E^T = mfma(Qv, R): C[row=q(reg), col=p(lane)] -> scratch ----
#pragma unroll
    for (int pt = 0; pt < 3; ++pt) {
      f32x16 e;
#pragma unroll
      for (int r = 0; r < 16; ++r) e[r] = 0.f;
#pragma unroll
      for (int s = 0; s < 4; ++s)
        e = __builtin_amdgcn_mfma_f32_32x32x16_bf16(qv[s], rf[pt * 4 + s], e, 0, 0, 0);
#pragma unroll
      for (int r = 0; r < 16; ++r) myscr[crow(r, hi) * 98 + pt * 32 + l31] = e[r];
    }

    // ---- S^T = mfma(K, Qu): C[row=k(reg), col=q(lane)] ----
    f32x16 s0, s1;
#pragma unroll
    for (int r = 0; r < 16; ++r) { s0[r] = 0.f; s1[r] = 0.f; }
#pragma unroll
    for (int s = 0; s < 4; ++s) {
      s0 = __builtin_amdgcn_mfma_f32_32x32x16_bf16(kf[s], qu[s], s0, 0, 0, 0);
      s1 = __builtin_amdgcn_mfma_f32_32x32x16_bf16(kf[4 + s], qu[s], s1, 0, 0, 0);
    }

    // ---- V loads (A-frags of O^T): row d, k-slice j0+ks*16+hi*8 ----
    bf16x8 vf[8];
#pragma unroll
    for (int dt = 0; dt < 2; ++dt)
#pragma unroll
      for (int ks = 0; ks < 4; ++ks)
        vf[dt * 4 + ks] =
            ld8(vbase + (int64_t)(dt * 32 + l31) * K_ + j0 + ks * 16 + hi * 8);

    // ---- S += E (lane-shifted read; stride-98 => conflict-free) ----
    const int rb0 = l31 * 98 + 31 - l31;
#pragma unroll
    for (int r = 0; r < 16; ++r) {
      int cc = rb0 + crow(r, hi);
      s0[r] = s0[r] + myscr[cc];
      s1[r] = s1[r] + myscr[cc + 32];
    }

    // ---- causal mask (final tile only) ----
    if (jt == njt - 1) {
#pragma unroll
      for (int r = 0; r < 16; ++r) {
        int ja = j0 + crow(r, hi);
        if (ja > q + MM_) s0[r] = -1e30f;
        if (ja + 32 > q + MM_) s1[r] = -1e30f;
      }
    }

    // ---- in-register online softmax (cross-half combine via shfl_xor 32) ----
    float mt = s0[0];
#pragma unroll
    for (int r = 1; r < 16; ++r) mt = fmaxf(mt, s0[r]);
#pragma unroll
    for (int r = 0; r < 16; ++r) mt = fmaxf(mt, s1[r]);
    mt = fmaxf(mt, __shfl_xor(mt, 32));
    float mnew = fmaxf(mrow, mt);
    float alpha = __expf(mrow - mnew);
    mrow = mnew;
    float rs = 0.f;
#pragma unroll
    for (int r = 0; r < 16; ++r) {
      s0[r] = __expf(s0[r] - mnew);
      rs += s0[r];
    }
#pragma unroll
    for (int r = 0; r < 16; ++r) {
      s1[r] = __expf(s1[r] - mnew);
      rs += s1[r];
    }
    rs += __shfl_xor(rs, 32);
    lsum = lsum * alpha + rs;
#pragma unroll
    for (int r = 0; r < 16; ++r) { o0a[r] *= alpha; o1a[r] *= alpha; }

    // ---- P fragments: cvt_pk + permlane32_swap (B-operand layout, col=q) ----
    // PSWAP(a,c): a=[a_lo|c_lo] -> w0, c=[a_hi|c_hi] -> w2 (low-pair FIRST; a!=c values).
    bf16x8 pf[4];
#pragma unroll
    for (int ks = 0; ks < 4; ++ks) {
      f32x16 sv = (ks < 2) ? s0 : s1;  // ks constant after unroll -> folds
      const int rb = (ks & 1) * 8;
      unsigned a = cvtpk(sv[rb + 0], sv[rb + 1]);
      unsigned b2 = cvtpk(sv[rb + 2], sv[rb + 3]);
      unsigned c = cvtpk(sv[rb + 4], sv[rb + 5]);
      unsigned d2 = cvtpk(sv[rb + 6], sv[rb + 7]);
      PSWAP(a, c);    // a -> w0, c -> w2
      PSWAP(b2, d2);  // b2 -> w1, d2 -> w3
      union { unsigned u4[4]; bf16x8 v; } pu;
      pu.u4[0] = a; pu.u4[1] = b2; pu.u4[2] = c; pu.u4[3] = d2;
      pf[ks] = pu.v;
    }

    // ---- O^T += V^T x P ----
#pragma unroll
    for (int ks = 0; ks < 4; ++ks) {
      o0a = __builtin_amdgcn_mfma_f32_32x32x16_bf16(vf[ks], pf[ks], o0a, 0, 0, 0);
      o1a = __builtin_amdgcn_mfma_f32_32x32x16_bf16(vf[4 + ks], pf[ks], o1a, 0, 0, 0);
    }
  }

  // ---- partial write-out: raw O (f32) + (m, l) ----
  float* Pc = chunk ? P1 : P0;
  float* prow_ = Pc + ((int64_t)(bh * Q_ + q) << 6);
#pragma unroll
  for (int g = 0; g < 4; ++g) {
    f32x4 t0 = {o0a[4 * g + 0], o0a[4 * g + 1], o0a[4 * g + 2], o0a[4 * g + 3]};
    f32x4 t1 = {o1a[4 * g + 0], o1a[4 * g + 1], o1a[4 * g + 2], o1a[4 * g + 3]};
    *(f32x4*)(prow_ + 8 * g + 4 * hi) = t0;
    *(f32x4*)(prow_ + 32 + 8 * g + 4 * hi) = t1;
  }
  if (hi == 0) {
    int mi = ((((chunk << 5) + bh) << 10) + q) << 1;
    mlbuf[mi] = mrow;
    mlbuf[mi + 1] = lsum;
  }
}

// ---------------- combine partials -> attnb (bf16) ----------------
__global__ __launch_bounds__(256) void k_combine(const float* __restrict__ P0,
                                                 const float* __restrict__ P1,
                                                 const float* __restrict__ mlbuf,
                                                 unsigned short* __restrict__ attnb) {
  int t = blockIdx.x * 256 + threadIdx.x;  // over 32768 rows x 64 cols
  int row = t >> 6, d = t & 63;
  int bh = row >> 10, i = row & (Q_ - 1), b = bh >> 4, h = bh & 15;
  int mi0 = ((bh << 10) + i) << 1;
  int mi1 = (((32 + bh) << 10) + i) << 1;
  float m0 = mlbuf[mi0], l0 = mlbuf[mi0 + 1];
  float m1 = mlbuf[mi1], l1 = mlbuf[mi1 + 1];
  float m = fmaxf(m0, m1);
  float a0 = __expf(m0 - m), a1 = __expf(m1 - m);
  float inv = 1.f / (a0 * l0 + a1 * l1);
  float o = (a0 * P0[t] + a1 * P1[t]) * inv;
  attnb[((int64_t)b * Q_ + i) * D_ + h * 64 + d] = f2bf(o);
}

// ---------------- launcher ----------------
extern "C" void kernel_launch(void* const* d_in, const int* in_sizes, int n_in, void* d_out,
                              int out_size, void* d_ws, size_t ws_size, hipStream_t stream) {
  const float* xin = (const float*)d_in[0];
  const float* xmem = (const float*)d_in[1];
  const float* rin = (const float*)d_in[2];
  const float* W = (const float*)d_in[3];
  const float* Wr = (const float*)d_in[4];
  const float* Wo = (const float*)d_in[5];
  const float* u = (const float*)d_in[6];
  const float* v = (const float*)d_in[7];
  float* out = (float*)d_out;

  char* ws = (char*)d_ws;
  size_t off = 0;
  auto take = [&](size_t n) {
    char* p = ws + off;
    off += (n + 255) & ~(size_t)255;
    return p;
  };
  unsigned short* Wt = (unsigned short*)take((size_t)D3_ * D_ * 2);   // 6 MiB (dead after QKV GEMM)
  unsigned short* Wrt = (unsigned short*)take((size_t)D_ * D_ * 2);   // 2 MiB (dead after r GEMM)
  unsigned short* Wot = (unsigned short*)take((size_t)D_ * D_ * 2);
  unsigned short* xcat = (unsigned short*)take((size_t)B_ * K_ * D_ * 2);  // 8 MiB (dead after QKV GEMM)
  unsigned short* rbf = (unsigned short*)take((size_t)K_ * D_ * 2);
  unsigned short* qhu = (unsigned short*)take((size_t)B_ * H_ * Q_ * DK_ * 2);
  unsigned short* qhv = (unsigned short*)take((size_t)B_ * H_ * Q_ * DK_ * 2);
  unsigned short* kh = (unsigned short*)take((size_t)B_ * H_ * K_ * DK_ * 2);
  unsigned short* vt = (unsigned short*)take((size_t)B_ * H_ * DK_ * K_ * 2);
  unsigned short* rh = (unsigned short*)take((size_t)H_ * K_ * DK_ * 2);
  float* mlbuf = (float*)take((size_t)2 * 32 * Q_ * 2 * 4);  // [chunk][bh][q][m,l]
  unsigned short* attnb = rbf;  // overlay: rbf dead after r-GEMM
  float* Pp0 = (float*)xcat;    // overlay: 8 MiB, chunk-0 raw O
  float* Pp1 = (float*)ws;      // overlay: Wt+Wrt = exactly 8 MiB, chunk-1 raw O

  if (ws_size < off) return;

  {
    int64_t total = (int64_t)B_ * K_ * D_ / 4 + (int64_t)K_ * D_ / 4;
    k_convert<<<dim3((unsigned)((total + 255) / 256)), 256, 0, stream>>>(xin, xmem, rin, xcat, rbf);
  }
  k_transw<<<dim3(D3_ / 32, D_ / 32), 256, 0, stream>>>(W, Wt, D_, D3_);
  k_transw<<<dim3(D_ / 32, D_ / 32), 256, 0, stream>>>(Wr, Wrt, D_, D_);
  k_transw<<<dim3(D_ / 32, D_ / 32), 256, 0, stream>>>(Wo, Wot, D_, D_);

  k_gemm128<0><<<dim3((B_ * K_) / 128, D3_ / 128), 256, 0, stream>>>(xcat, Wt, qhu, kh, vt, qhv, u, v, nullptr);
  k_gemm128<1><<<dim3(K_ / 128, D_ / 128), 256, 0, stream>>>(rbf, Wrt, rh, nullptr, nullptr, nullptr, nullptr, nullptr, nullptr);

  k_attn<<<dim3(Q_ / 64, B_ * H_, 2), 128, 0, stream>>>(qhu, qhv, kh, vt, rh, Pp0, Pp1, mlbuf);
  k_combine<<<dim3((B_ * H_ * Q_ * DK_) / 256), 256, 0, stream>>>(Pp0, Pp1, mlbuf, attnb);

  k_gemm128<2><<<dim3((B_ * Q_) / 128, D_ / 128), 256, 0, stream>>>(attnb, Wot, nullptr, nullptr, nullptr, nullptr, nullptr, nullptr, out);
}